// Round 1
// baseline (6011.195 us; speedup 1.0000x reference)
//
#include <hip/hip_runtime.h>

#define NBS    256
#define NELEC  64
#define NPART  80
#define NBASIS 32
#define KD     128
#define DD     128

// shifted softplus: softplus(x) - ln 2, stable form
__device__ __forceinline__ float sspf(float x) {
    return fmaxf(x, 0.0f) + log1pf(expf(-fabsf(x))) - 0.69314718055994530942f;
}

__device__ __forceinline__ float bf2f(unsigned short u) {
    unsigned int x = ((unsigned int)u) << 16;
    return __builtin_bit_cast(float, x);
}
__device__ __forceinline__ unsigned short f2bf(float f) {
    unsigned int x = __builtin_bit_cast(unsigned int, f);
    x += 0x7fffu + ((x >> 16) & 1u);
    return (unsigned short)(x >> 16);
}

// xs[b,i,:] = embedding_elec[i,:]
__global__ __launch_bounds__(256) void k_init_xs(const float* __restrict__ emb,
                                                 float* __restrict__ xs) {
    int idx = blockIdx.x * 256 + threadIdx.x;
    xs[idx] = emb[idx & (NELEC * DD - 1)];
}

// Y[b, 0..63, :] = (opt ssp)(X[b, 0..63, :] @ W + bias) (opt += into Y)
// one block per b; 64x128 rows tile, weights streamed from L2.
// If nuc != null, also writes Y[b, 64..79, :] = nuc (zs concat rows).
template <int ACT, int ACCUM>
__global__ __launch_bounds__(256) void k_small_gemm(
    const float* __restrict__ X, int xStride,
    const float* __restrict__ W, const float* __restrict__ bias,
    float* __restrict__ Y, int yStride,
    const float* __restrict__ nuc) {
    __shared__ float s_x[NELEC * DD];
    const int b = blockIdx.x;
    const int t = threadIdx.x;

    const float4* Xv = (const float4*)(X + (size_t)b * xStride);
    float4* sv = (float4*)s_x;
#pragma unroll
    for (int e = 0; e < 8; ++e) sv[t + 256 * e] = Xv[t + 256 * e];

    if (nuc) {
        float* zb = Y + (size_t)b * yStride + NELEC * KD;
#pragma unroll
        for (int e = 0; e < 8; ++e) zb[t + 256 * e] = nuc[t + 256 * e];
    }
    __syncthreads();

    const int k = t & 127;
    const int j0 = (t >> 7) * 32;
    float bv = bias ? bias[k] : 0.0f;
    float acc[32];
#pragma unroll
    for (int jj = 0; jj < 32; ++jj) acc[jj] = bv;

    for (int m = 0; m < DD; ++m) {
        float w = W[m * KD + k];
#pragma unroll
        for (int jj = 0; jj < 32; ++jj)
            acc[jj] += s_x[(j0 + jj) * DD + m] * w;
    }

    float* Yb = Y + (size_t)b * yStride;
#pragma unroll
    for (int jj = 0; jj < 32; ++jj) {
        float v = acc[jj];
        if (ACT) v = sspf(v);
        size_t o = (size_t)(j0 + jj) * KD + k;
        if (ACCUM) Yb[o] += v;
        else Yb[o] = v;
    }
}

// one block per (b,i): fused  X1 = ssp(dists@kW1+kb1) ; Ws = X1@kW2+kb2 (mask j==i)
// agg[b,i,k] = sum_j Ws[j,k] * zs[b,j,k]
__global__ __launch_bounds__(256) void k_cfconv(
    const float* __restrict__ dists,
    const float* __restrict__ kW1, const float* __restrict__ kb1,
    const float* __restrict__ kW2g, const float* __restrict__ kb2,
    const float* __restrict__ zs,
    float* __restrict__ agg) {
    __shared__ __align__(16) char smem[57344];
    float* s_dists = (float*)smem;                            // 80*32 f32   (ph1-2)
    float* s_kW1   = (float*)(smem + 10240);                  // 32*128 f32  (ph1-2)
    unsigned short* s_kW2 = (unsigned short*)smem;            // 128*128 bf16 (ph3, alias)
    unsigned short* s_X1  = (unsigned short*)(smem + 32768);  // 80*128 bf16
    float* s_red   = (float*)(smem + 53248);                  // 8*128 f32

    const int bid = blockIdx.x;
    const int i = bid & 63;
    const int b = bid >> 6;
    const int t = threadIdx.x;

    // phase 1: stage dists tile + kW1
    {
        const float4* dv = (const float4*)(dists + (size_t)bid * (NPART * NBASIS));
        float4* sdv = (float4*)s_dists;
        for (int e = t; e < (NPART * NBASIS) / 4; e += 256) sdv[e] = dv[e];
        const float4* wv = (const float4*)kW1;
        float4* swv = (float4*)s_kW1;
#pragma unroll
        for (int e = 0; e < 4; ++e) swv[t + 256 * e] = wv[t + 256 * e];
    }
    __syncthreads();

    // phase 2: X1[j,k] = ssp(dists[j,:]@kW1[:,k] + kb1[k]) -> bf16 LDS
    {
        const int k = t & 127;
        const int jh = t >> 7;
        const float b1 = kb1[k];
        for (int j = jh; j < NPART; j += 2) {
            float acc = b1;
#pragma unroll
            for (int f = 0; f < NBASIS; ++f)
                acc += s_dists[j * NBASIS + f] * s_kW1[f * KD + k];
            s_X1[j * KD + k] = f2bf(sspf(acc));
        }
    }
    __syncthreads();

    // phase 2.5: stage kW2 as bf16 (aliases dists/kW1 region)
    for (int e = t; e < KD * KD; e += 256) s_kW2[e] = f2bf(kW2g[e]);
    __syncthreads();

    // phase 3: Ws[j,k] = X1[j,:]@kW2[:,k] + kb2[k];  acc[k] += Ws[j,k]*zs[b,j,k]
    {
        const int kk = (t & 31) * 4;
        const int jg = t >> 5;
        const float* zsb = zs + (size_t)b * (NPART * KD);
        float4 acc = {0.f, 0.f, 0.f, 0.f};
        const float4 b2 = *(const float4*)(kb2 + kk);
        for (int j = jg; j < NPART; j += 8) {
            if (j == i) continue;  // ZeroDiagKernel mask
            float4 w = b2;
            const unsigned short* x1row = s_X1 + j * KD;
#pragma unroll 8
            for (int m = 0; m < KD; ++m) {
                float x = bf2f(x1row[m]);
                ushort4 c = *(const ushort4*)(s_kW2 + m * KD + kk);
                w.x += x * bf2f(c.x);
                w.y += x * bf2f(c.y);
                w.z += x * bf2f(c.z);
                w.w += x * bf2f(c.w);
            }
            float4 z = *(const float4*)(zsb + j * KD + kk);
            acc.x += w.x * z.x;
            acc.y += w.y * z.y;
            acc.z += w.z * z.z;
            acc.w += w.w * z.w;
        }
        *(float4*)(s_red + jg * KD + kk) = acc;
    }
    __syncthreads();
    if (t < KD) {
        float s = 0.f;
#pragma unroll
        for (int g = 0; g < 8; ++g) s += s_red[g * KD + t];
        agg[(size_t)bid * KD + t] = s;
    }
}

extern "C" void kernel_launch(void* const* d_in, const int* in_sizes, int n_in,
                              void* d_out, int out_size, void* d_ws, size_t ws_size,
                              hipStream_t stream) {
    const float* dists = (const float*)d_in[0];
    const float* emb_e = (const float*)d_in[1];
    const float* emb_n = (const float*)d_in[2];
    const float* kW1   = (const float*)d_in[3];
    const float* kb1   = (const float*)d_in[4];
    const float* kW2   = (const float*)d_in[5];
    const float* kb2   = (const float*)d_in[6];
    const float* eiW   = (const float*)d_in[7];
    const float* eoW1  = (const float*)d_in[8];
    const float* eob1  = (const float*)d_in[9];
    const float* eoW2  = (const float*)d_in[10];
    const float* eob2  = (const float*)d_in[11];

    float* xs  = (float*)d_out;                 // (256,64,128)
    float* zs  = (float*)d_ws;                  // (256,80,128); h aliases elec rows
    float* agg = zs + NBS * NPART * KD;         // (256,64,128)

    k_init_xs<<<(NBS * NELEC * DD) / 256, 256, 0, stream>>>(emb_e, xs);

    for (int l = 0; l < 3; ++l) {
        // zs[:, :64] = xs @ eiW[l]; zs[:, 64:] = nuc (written at l==0, stays valid)
        k_small_gemm<0, 0><<<NBS, 256, 0, stream>>>(
            xs, NELEC * DD, eiW + l * DD * KD, nullptr,
            zs, NPART * KD, (l == 0) ? emb_n : nullptr);

        k_cfconv<<<NBS * NELEC, 256, 0, stream>>>(
            dists, kW1 + l * NBASIS * KD, kb1 + l * KD,
            kW2 + l * KD * KD, kb2 + l * KD, zs, agg);

        // h = ssp(agg @ eoW1 + eob1)  (h stored into zs electron rows)
        k_small_gemm<1, 0><<<NBS, 256, 0, stream>>>(
            agg, NELEC * KD, eoW1 + l * KD * DD, eob1 + l * DD,
            zs, NPART * KD, nullptr);

        // xs += h @ eoW2 + eob2
        k_small_gemm<0, 1><<<NBS, 256, 0, stream>>>(
            zs, NPART * KD, eoW2 + l * DD * DD, eob2 + l * DD,
            xs, NELEC * DD, nullptr);
    }
}

// Round 2
// 2197.509 us; speedup vs baseline: 2.7355x; 2.7355x over previous
//
#include <hip/hip_runtime.h>

#define NBS    256
#define NELEC  64
#define NPART  80
#define NBASIS 32
#define KD     128
#define DD     128

typedef short v8s __attribute__((ext_vector_type(8)));
typedef float v4f __attribute__((ext_vector_type(4)));

// shifted softplus: softplus(x) - ln 2, stable form
__device__ __forceinline__ float sspf(float x) {
    return fmaxf(x, 0.0f) + log1pf(expf(-fabsf(x))) - 0.69314718055994530942f;
}

__device__ __forceinline__ float bf2f(unsigned short u) {
    unsigned int x = ((unsigned int)u) << 16;
    return __builtin_bit_cast(float, x);
}
__device__ __forceinline__ unsigned short f2bf(float f) {
    unsigned int x = __builtin_bit_cast(unsigned int, f);
    x += 0x7fffu + ((x >> 16) & 1u);
    return (unsigned short)(x >> 16);
}

// xs[b,i,:] = embedding_elec[i,:]
__global__ __launch_bounds__(256) void k_init_xs(const float* __restrict__ emb,
                                                 float* __restrict__ xs) {
    int idx = blockIdx.x * 256 + threadIdx.x;
    xs[idx] = emb[idx & (NELEC * DD - 1)];
}

// Pre-swizzle kW1/kW2 (per layer) into MFMA A-operand fragment order, bf16.
// A-frag: lane holds A[m = lane&15][k = (lane>>4)*8 + jj], jj=0..7.
// kW2Tf layout: [l][mt'(8)][ks(4)][lane(64)][jj(8)]  (A'[kcol][kf] = kW2[kf][kcol])
// kW1Tf layout: [l][kct(8)][lane(64)][jj(8)]         (A'[kcol][f]  = kW1[f][kcol])
__global__ __launch_bounds__(256) void k_prep(const float* __restrict__ kW1g,
                                              const float* __restrict__ kW2g,
                                              unsigned short* __restrict__ kW1Tf,
                                              unsigned short* __restrict__ kW2Tf) {
    const int l = blockIdx.x;
    const int t = threadIdx.x;
    for (int e = 0; e < 64; ++e) {
        int o = e * 256 + t;                       // < 16384
        int mt = o >> 11, ks = (o >> 9) & 3, lane = (o >> 3) & 63, jj = o & 7;
        int q = lane >> 4, cc = lane & 15;
        int kf = ks * 32 + q * 8 + jj;
        int kcol = mt * 16 + cc;
        kW2Tf[(size_t)l * 16384 + o] = f2bf(kW2g[(size_t)l * 16384 + kf * 128 + kcol]);
    }
    for (int e = 0; e < 16; ++e) {
        int o = e * 256 + t;                       // < 4096
        int kct = o >> 9, lane = (o >> 3) & 63, jj = o & 7;
        int q = lane >> 4, cc = lane & 15;
        int f = q * 8 + jj;
        int kcol = kct * 16 + cc;
        kW1Tf[(size_t)l * 4096 + o] = f2bf(kW1g[(size_t)l * 4096 + f * 128 + kcol]);
    }
}

// Y[b, 0..63, :] = (opt ssp)(X[b, 0..63, :] @ W + bias) (opt += into Y)
template <int ACT, int ACCUM>
__global__ __launch_bounds__(256) void k_small_gemm(
    const float* __restrict__ X, int xStride,
    const float* __restrict__ W, const float* __restrict__ bias,
    float* __restrict__ Y, int yStride,
    const float* __restrict__ nuc) {
    __shared__ float s_x[NELEC * DD];
    const int b = blockIdx.x;
    const int t = threadIdx.x;

    const float4* Xv = (const float4*)(X + (size_t)b * xStride);
    float4* sv = (float4*)s_x;
#pragma unroll
    for (int e = 0; e < 8; ++e) sv[t + 256 * e] = Xv[t + 256 * e];

    if (nuc) {
        float* zb = Y + (size_t)b * yStride + NELEC * KD;
#pragma unroll
        for (int e = 0; e < 8; ++e) zb[t + 256 * e] = nuc[t + 256 * e];
    }
    __syncthreads();

    const int k = t & 127;
    const int j0 = (t >> 7) * 32;
    float bv = bias ? bias[k] : 0.0f;
    float acc[32];
#pragma unroll
    for (int jj = 0; jj < 32; ++jj) acc[jj] = bv;

    for (int m = 0; m < DD; ++m) {
        float w = W[m * KD + k];
#pragma unroll
        for (int jj = 0; jj < 32; ++jj)
            acc[jj] += s_x[(j0 + jj) * DD + m] * w;
    }

    float* Yb = Y + (size_t)b * yStride;
#pragma unroll
    for (int jj = 0; jj < 32; ++jj) {
        float v = acc[jj];
        if (ACT) v = sspf(v);
        size_t o = (size_t)(j0 + jj) * KD + k;
        if (ACCUM) Yb[o] += v;
        else Yb[o] = v;
    }
}

// One block per (b,i). Transposed MFMA formulation:
//   GEMM1-T: X1T[kcol][j] = ssp( sum_f kW1T[kcol][f]*dists[j][f] + kb1[kcol] )
//   GEMM2-T: WsT[kcol][j] = sum_kf kW2T[kcol][kf]*X1T[kf][j]  (+kb2 on kh==0 waves)
//   agg[kcol] = sum_j WsT[kcol][j]*zs[j][kcol]   (zs row i zeroed = diag mask)
// Wave w: h = w>>1 owns kcol-half (4 mt' tiles), kh = w&1 owns kf-half (2 ksteps).
__global__ __launch_bounds__(256) void k_cfconv_mfma(
    const float* __restrict__ dists,
    const float* __restrict__ kb1g, const float* __restrict__ kb2g,
    const float* __restrict__ zsg,
    const unsigned short* __restrict__ kW1Tf,
    const unsigned short* __restrict__ kW2Tf,
    float* __restrict__ agg, int l) {
    __shared__ __align__(16) unsigned short s_mem[23360];  // 46720 B
    __shared__ __align__(16) float s_red[256];
    unsigned short* s_dists = s_mem;          // [jt(5)][lane(64)][jj(8)]   B-frags of dists
    unsigned short* s_X1    = s_mem + 2560;   // [jt(5)][ks(4)][lane(64)][jj(8)] B-frags of X1
    unsigned short* s_zs    = s_mem + 12800;  // [j(80)][k pad 132] bf16 row-major

    const int bid = blockIdx.x;
    const int i = bid & 63;
    const int b = bid >> 6;
    const int t = threadIdx.x;
    const int lane = t & 63;
    const int w = t >> 6;
    const int q = lane >> 4;
    const int c = lane & 15;
    const int h = w >> 1;
    const int kh = w & 1;

    // --- A'-fragment register preloads (L2-broadcast weights) ---
    v8s a1[2], a2[4][2];
    {
        const uint4* w1p = (const uint4*)kW1Tf;
        const uint4* w2p = (const uint4*)kW2Tf;
#pragma unroll
        for (int t1 = 0; t1 < 2; ++t1) {
            uint4 u = w1p[(l * 8 + 2 * w + t1) * 64 + lane];
            a1[t1] = __builtin_bit_cast(v8s, u);
        }
#pragma unroll
        for (int mt = 0; mt < 4; ++mt)
#pragma unroll
            for (int t1 = 0; t1 < 2; ++t1) {
                uint4 u = w2p[((l * 8 + h * 4 + mt) * 4 + kh * 2 + t1) * 64 + lane];
                a2[mt][t1] = __builtin_bit_cast(v8s, u);
            }
    }
    float kb1v[2][4], kb2v[4][4];
#pragma unroll
    for (int t1 = 0; t1 < 2; ++t1)
#pragma unroll
        for (int r = 0; r < 4; ++r)
            kb1v[t1][r] = kb1g[l * 128 + (2 * w + t1) * 16 + q * 4 + r];
#pragma unroll
    for (int mt = 0; mt < 4; ++mt)
#pragma unroll
        for (int r = 0; r < 4; ++r)
            kb2v[mt][r] = kh ? 0.0f : kb2g[l * 128 + (h * 4 + mt) * 16 + q * 4 + r];

    // --- stage dists into B-frag order (bf16) ---
    {
        const float* dg = dists + (size_t)bid * (NPART * NBASIS);
#pragma unroll
        for (int e = 0; e < 10; ++e) {
            int idx = e * 256 + t;
            float v = dg[idx];
            int j = idx >> 5, f = idx & 31;
            s_dists[((j >> 4) * 64 + (f >> 3) * 16 + (j & 15)) * 8 + (f & 7)] = f2bf(v);
        }
    }
    // --- stage zs (bf16, stride 132, zero row i = diag mask) ---
    {
        const float4* zg = (const float4*)zsg + (size_t)b * 2560;
#pragma unroll
        for (int e = 0; e < 10; ++e) {
            int idx4 = e * 256 + t;
            int j = idx4 >> 5, k4 = (idx4 & 31) * 4;
            float4 v = zg[idx4];
            ushort4 o;
            if (j == i) {
                o.x = 0; o.y = 0; o.z = 0; o.w = 0;
            } else {
                o.x = f2bf(v.x); o.y = f2bf(v.y); o.z = f2bf(v.z); o.w = f2bf(v.w);
            }
            *(ushort4*)(s_zs + j * 132 + k4) = o;
        }
    }
    __syncthreads();

    // --- GEMM1-T: 10 MFMA, ssp, write X1 B-frags (b64, exact frag order) ---
#pragma unroll
    for (int jt = 0; jt < 5; ++jt) {
        v8s bd = *(const v8s*)(s_dists + (jt * 64 + lane) * 8);
#pragma unroll
        for (int t1 = 0; t1 < 2; ++t1) {
            v4f d = {kb1v[t1][0], kb1v[t1][1], kb1v[t1][2], kb1v[t1][3]};
            d = __builtin_amdgcn_mfma_f32_16x16x32_bf16(a1[t1], bd, d, 0, 0, 0);
            ushort4 o;
            o.x = f2bf(sspf(d[0]));
            o.y = f2bf(sspf(d[1]));
            o.z = f2bf(sspf(d[2]));
            o.w = f2bf(sspf(d[3]));
            int qB = 2 * t1 + (q >> 1);  // ks = w for both t1 (kct = 2w+t1)
            *(ushort4*)(s_X1 + ((jt * 4 + w) * 64 + qB * 16 + c) * 8 + (q & 1) * 4) = o;
        }
    }
    __syncthreads();

    // --- GEMM2-T: 40 MFMA over this wave's (4 mt', 5 jt, 2 ks) ---
    v4f acc[4][5];
#pragma unroll
    for (int mt = 0; mt < 4; ++mt)
#pragma unroll
        for (int jt = 0; jt < 5; ++jt)
            acc[mt][jt] = (v4f){kb2v[mt][0], kb2v[mt][1], kb2v[mt][2], kb2v[mt][3]};

#pragma unroll
    for (int jt = 0; jt < 5; ++jt) {
        v8s bx0 = *(const v8s*)(s_X1 + ((jt * 4 + kh * 2) * 64 + lane) * 8);
        v8s bx1 = *(const v8s*)(s_X1 + ((jt * 4 + kh * 2 + 1) * 64 + lane) * 8);
#pragma unroll
        for (int mt = 0; mt < 4; ++mt) {
            acc[mt][jt] = __builtin_amdgcn_mfma_f32_16x16x32_bf16(a2[mt][0], bx0, acc[mt][jt], 0, 0, 0);
            acc[mt][jt] = __builtin_amdgcn_mfma_f32_16x16x32_bf16(a2[mt][1], bx1, acc[mt][jt], 0, 0, 0);
        }
    }

    // --- multiply by zs and reduce over j (within-lane over jt, cross-lane over c) ---
    float red[4][4];
#pragma unroll
    for (int mt = 0; mt < 4; ++mt)
#pragma unroll
        for (int r = 0; r < 4; ++r) red[mt][r] = 0.0f;

#pragma unroll
    for (int mt = 0; mt < 4; ++mt)
#pragma unroll
        for (int jt = 0; jt < 5; ++jt) {
            ushort4 zv = *(const ushort4*)(s_zs + (jt * 16 + c) * 132 + (h * 4 + mt) * 16 + q * 4);
            red[mt][0] += acc[mt][jt][0] * bf2f(zv.x);
            red[mt][1] += acc[mt][jt][1] * bf2f(zv.y);
            red[mt][2] += acc[mt][jt][2] * bf2f(zv.z);
            red[mt][3] += acc[mt][jt][3] * bf2f(zv.w);
        }

    // distributed butterfly: 16 values -> 1 per lane (lane c gets value v=c)
    float vals[16];
#pragma unroll
    for (int m = 0; m < 4; ++m)
#pragma unroll
        for (int r = 0; r < 4; ++r) vals[m * 4 + r] = red[m][r];
#pragma unroll
    for (int B = 0; B < 4; ++B) {
        const int off = 1 << B;
        const bool up = (c >> B) & 1;
#pragma unroll
        for (int k2 = 0; k2 < (8 >> B); ++k2) {
            float aa = vals[2 * k2], bb = vals[2 * k2 + 1];
            float mine = up ? bb : aa;
            float other = up ? aa : bb;
            vals[k2] = mine + __shfl_xor(other, off, 64);
        }
    }
    s_red[w * 64 + ((c >> 2) * 16 + q * 4 + (c & 3))] = vals[0];
    __syncthreads();

    if (t < 128) {
        int hh = t >> 6, kk = t & 63;
        agg[(size_t)bid * 128 + t] = s_red[hh * 128 + kk] + s_red[hh * 128 + 64 + kk];
    }
}

extern "C" void kernel_launch(void* const* d_in, const int* in_sizes, int n_in,
                              void* d_out, int out_size, void* d_ws, size_t ws_size,
                              hipStream_t stream) {
    const float* dists = (const float*)d_in[0];
    const float* emb_e = (const float*)d_in[1];
    const float* emb_n = (const float*)d_in[2];
    const float* kW1   = (const float*)d_in[3];
    const float* kb1   = (const float*)d_in[4];
    const float* kW2   = (const float*)d_in[5];
    const float* kb2   = (const float*)d_in[6];
    const float* eiW   = (const float*)d_in[7];
    const float* eoW1  = (const float*)d_in[8];
    const float* eob1  = (const float*)d_in[9];
    const float* eoW2  = (const float*)d_in[10];
    const float* eob2  = (const float*)d_in[11];

    float* xs  = (float*)d_out;                 // (256,64,128)
    float* zs  = (float*)d_ws;                  // (256,80,128); h aliases elec rows
    float* agg = zs + NBS * NPART * KD;         // (256,64,128)
    unsigned short* kW1Tf = (unsigned short*)(agg + NBS * NELEC * KD);  // 3*4096
    unsigned short* kW2Tf = kW1Tf + 3 * 4096;                            // 3*16384

    k_init_xs<<<(NBS * NELEC * DD) / 256, 256, 0, stream>>>(emb_e, xs);
    k_prep<<<3, 256, 0, stream>>>(kW1, kW2, kW1Tf, kW2Tf);

    for (int l = 0; l < 3; ++l) {
        // zs[:, :64] = xs @ eiW[l]; zs[:, 64:] = nuc (written at l==0, stays valid)
        k_small_gemm<0, 0><<<NBS, 256, 0, stream>>>(
            xs, NELEC * DD, eiW + l * DD * KD, nullptr,
            zs, NPART * KD, (l == 0) ? emb_n : nullptr);

        k_cfconv_mfma<<<NBS * NELEC, 256, 0, stream>>>(
            dists, kb1, kb2, zs, kW1Tf, kW2Tf, agg, l);

        // h = ssp(agg @ eoW1 + eob1)  (h stored into zs electron rows)
        k_small_gemm<1, 0><<<NBS, 256, 0, stream>>>(
            agg, NELEC * KD, eoW1 + l * KD * DD, eob1 + l * DD,
            zs, NPART * KD, nullptr);

        // xs += h @ eoW2 + eob2
        k_small_gemm<0, 1><<<NBS, 256, 0, stream>>>(
            zs, NPART * KD, eoW2 + l * DD * DD, eob2 + l * DD,
            xs, NELEC * DD, nullptr);
    }
}

// Round 3
// 1119.494 us; speedup vs baseline: 5.3696x; 1.9629x over previous
//
#include <hip/hip_runtime.h>

#define NBS    256
#define NELEC  64
#define NPART  80
#define NBASIS 32
#define KD     128
#define DD     128

typedef short v8s __attribute__((ext_vector_type(8)));
typedef float v4f __attribute__((ext_vector_type(4)));

// fast shifted softplus: log(1+e^x) - ln2 via HW exp2/log2 (inputs bounded, |x| << 88)
__device__ __forceinline__ float sspf(float x) {
    float t = __expf(x);
    return __logf(1.0f + t) - 0.69314718055994530942f;
}

__device__ __forceinline__ float bf2f(unsigned short u) {
    unsigned int x = ((unsigned int)u) << 16;
    return __builtin_bit_cast(float, x);
}
__device__ __forceinline__ unsigned short f2bf(float f) {
    unsigned int x = __builtin_bit_cast(unsigned int, f);
    x += 0x7fffu + ((x >> 16) & 1u);
    return (unsigned short)(x >> 16);
}
__device__ __forceinline__ unsigned int pk2(float lo, float hi) {
    return (unsigned int)f2bf(lo) | ((unsigned int)f2bf(hi) << 16);
}

// xs[b,i,:] = embedding_elec[i,:] (f32 master + bf16 mirror)
__global__ __launch_bounds__(256) void k_init_xs(const float* __restrict__ emb,
                                                 float* __restrict__ xs,
                                                 unsigned short* __restrict__ xs_bf) {
    int idx = blockIdx.x * 256 + threadIdx.x;
    float v = emb[idx & (NELEC * DD - 1)];
    xs[idx] = v;
    xs_bf[idx] = f2bf(v);
}

// zsbf nuc rows: zsbf[b, 64+j, k] = bf16(nuc[j,k])
__global__ __launch_bounds__(256) void k_nuc(const float* __restrict__ nuc,
                                             unsigned short* __restrict__ zsbf) {
    int idx = blockIdx.x * 256 + threadIdx.x;           // < 256*16*128
    int b = idx >> 11;
    int rem = idx & 2047;
    zsbf[(size_t)b * (NPART * KD) + NELEC * KD + rem] = f2bf(nuc[rem]);
}

// Pre-swizzle kW1/kW2 (per layer) into MFMA A-operand fragment order, bf16.
// A-frag: lane holds A[m = lane&15][k = (lane>>4)*8 + jj], jj=0..7.
// kW2Tf layout: [l][mt'(8)][ks(4)][lane(64)][jj(8)]  (A'[kcol][kf] = kW2[kf][kcol])
// kW1Tf layout: [l][kct(8)][lane(64)][jj(8)]         (A'[kcol][f]  = kW1[f][kcol])
__global__ __launch_bounds__(256) void k_prep(const float* __restrict__ kW1g,
                                              const float* __restrict__ kW2g,
                                              unsigned short* __restrict__ kW1Tf,
                                              unsigned short* __restrict__ kW2Tf) {
    const int l = blockIdx.x;
    const int t = threadIdx.x;
    for (int e = 0; e < 64; ++e) {
        int o = e * 256 + t;                       // < 16384
        int mt = o >> 11, ks = (o >> 9) & 3, lane = (o >> 3) & 63, jj = o & 7;
        int q = lane >> 4, cc = lane & 15;
        int kf = ks * 32 + q * 8 + jj;
        int kcol = mt * 16 + cc;
        kW2Tf[(size_t)l * 16384 + o] = f2bf(kW2g[(size_t)l * 16384 + kf * 128 + kcol]);
    }
    for (int e = 0; e < 16; ++e) {
        int o = e * 256 + t;                       // < 4096
        int kct = o >> 9, lane = (o >> 3) & 63, jj = o & 7;
        int q = lane >> 4, cc = lane & 15;
        int f = q * 8 + jj;
        int kcol = kct * 16 + cc;
        kW1Tf[(size_t)l * 4096 + o] = f2bf(kW1g[(size_t)l * 4096 + f * 128 + kcol]);
    }
}

// B-operand fragment swizzle for the small gemms' weights (9 matrices 128x128).
// Wf[bi][mt(8)][ks(4)][lane(64)][jj(8)] = W[ks*32+q*8+jj][mt*16+c]
__global__ __launch_bounds__(256) void k_prep_w(const float* __restrict__ eiW,
                                                const float* __restrict__ eoW1,
                                                const float* __restrict__ eoW2,
                                                unsigned short* __restrict__ Wf) {
    const int bi = blockIdx.x;          // 0..8 : which*3 + l
    const int which = bi / 3, l = bi % 3;
    const float* src = (which == 0 ? eiW : which == 1 ? eoW1 : eoW2) + (size_t)l * 16384;
    unsigned short* dst = Wf + (size_t)bi * 16384;
    const int t = threadIdx.x;
    for (int e = 0; e < 64; ++e) {
        int o = e * 256 + t;
        int mt = o >> 11, ks = (o >> 9) & 3, lane = (o >> 3) & 63, jj = o & 7;
        int q = lane >> 4, cc = lane & 15;
        dst[o] = f2bf(src[(ks * 32 + q * 8 + jj) * 128 + mt * 16 + cc]);
    }
}

// bias fragments for cfconv: kb1f[l][w(4)][lane(64)][8], kb2f[l][w(4)][lane(64)][16]
__global__ __launch_bounds__(256) void k_prep_misc(const float* __restrict__ kb1,
                                                   const float* __restrict__ kb2,
                                                   float* __restrict__ kb1f,
                                                   float* __restrict__ kb2f) {
    const int t = threadIdx.x;
    for (int o = t; o < 3 * 4 * 64 * 8; o += 256) {
        int l = o >> 11, rem = o & 2047;
        int w = rem >> 9, lane = (rem >> 3) & 63, e = o & 7;
        int t1 = e >> 2, r = e & 3, q = lane >> 4;
        kb1f[o] = kb1[l * 128 + (2 * w + t1) * 16 + q * 4 + r];
    }
    for (int o = t; o < 3 * 4 * 64 * 16; o += 256) {
        int l = o >> 12, rem = o & 4095;
        int w = rem >> 10, lane = (rem >> 4) & 63, e = o & 15;
        int mt = e >> 2, r = e & 3, q = lane >> 4;
        int kh = w & 1, h = w >> 1;
        kb2f[o] = kh ? 0.0f : kb2[l * 128 + (h * 4 + mt) * 16 + q * 4 + r];
    }
}

// MFMA small gemm: C(64x128) = X(64x128,bf16) @ W(frag bf16)  [+bias][+ssp]
// MODE 0: zs   (no bias/act, out bf16 stride ostride)
// MODE 1: h    (bias+ssp, out bf16)
// MODE 2: upd  (bias, xs_f32 += C, store f32 + bf16 mirror)
// grid: NBS*2 blocks; block = (b, k-half). wave w owns rows w*16..w*16+15.
template <int MODE>
__global__ __launch_bounds__(256) void k_gemm(
    const unsigned short* __restrict__ Xbf,
    const unsigned short* __restrict__ Wf,
    const float* __restrict__ bias,
    unsigned short* __restrict__ Obf,
    float* __restrict__ Of,
    int ostride) {
    const int blk = blockIdx.x;
    const int b = blk >> 1, kh2 = blk & 1;
    const int t = threadIdx.x, lane = t & 63, w = t >> 6;
    const int q = lane >> 4, c = lane & 15;

    const unsigned short* xb = Xbf + (size_t)b * (NELEC * KD);
    v8s A[4];
#pragma unroll
    for (int ks = 0; ks < 4; ++ks)
        A[ks] = *(const v8s*)(xb + (w * 16 + c) * 128 + ks * 32 + q * 8);

#pragma unroll
    for (int kt = 0; kt < 4; ++kt) {
        const int n0 = kh2 * 64 + kt * 16;
        float bv = (MODE >= 1) ? bias[n0 + c] : 0.0f;
        v4f acc = {bv, bv, bv, bv};
#pragma unroll
        for (int ks = 0; ks < 4; ++ks) {
            v8s B = *(const v8s*)(Wf + (((size_t)(kh2 * 4 + kt) * 4 + ks) * 64 + lane) * 8);
            acc = __builtin_amdgcn_mfma_f32_16x16x32_bf16(A[ks], B, acc, 0, 0, 0);
        }
#pragma unroll
        for (int r = 0; r < 4; ++r) {
            float v = acc[r];
            if (MODE == 1) v = sspf(v);
            int row = w * 16 + q * 4 + r, col = n0 + c;
            if (MODE == 2) {
                size_t o = (size_t)b * (NELEC * KD) + row * 128 + col;
                float nv = Of[o] + v;
                Of[o] = nv;
                Obf[o] = f2bf(nv);
            } else {
                Obf[(size_t)b * ostride + row * 128 + col] = f2bf(v);
            }
        }
    }
}

// One block per (b,i). Transposed MFMA formulation (verified R2 index math):
//   GEMM1-T: X1T[kcol][j] = ssp( sum_f kW1T[kcol][f]*dists[j][f] + kb1[kcol] )
//   GEMM2-T: WsT[kcol][j] = sum_kf kW2T[kcol][kf]*X1T[kf][j]  (+kb2 on kh==0 waves)
//   agg[kcol] = sum_j WsT[kcol][j]*zsbf[b][j][kcol]  (j==i masked)
__global__ __launch_bounds__(256) void k_cfconv_mfma(
    const float* __restrict__ dists,
    const float* __restrict__ kb1f, const float* __restrict__ kb2f,
    const unsigned short* __restrict__ zsbf,
    const unsigned short* __restrict__ kW1Tf,
    const unsigned short* __restrict__ kW2Tf,
    unsigned short* __restrict__ aggbf, int l) {
    __shared__ __align__(16) unsigned short s_dists[2560];   // [jt(5)][lane(64)][jj(8)]
    __shared__ __align__(16) unsigned short s_X1[10240];     // [jt(5)][ks(4)][lane(64)][jj(8)]
    __shared__ __align__(16) float s_red[256];

    const int bid = blockIdx.x;
    const int i = bid & 63;
    const int b = bid >> 6;
    const int t = threadIdx.x;
    const int lane = t & 63;
    const int w = t >> 6;
    const int q = lane >> 4;
    const int c = lane & 15;
    const int h = w >> 1;
    const int kh = w & 1;

    // A'-fragment weights (L2-broadcast)
    v8s a1[2], a2[4][2];
    {
        const uint4* w1p = (const uint4*)kW1Tf;
        const uint4* w2p = (const uint4*)kW2Tf;
#pragma unroll
        for (int t1 = 0; t1 < 2; ++t1) {
            uint4 u = w1p[(l * 8 + 2 * w + t1) * 64 + lane];
            a1[t1] = __builtin_bit_cast(v8s, u);
        }
#pragma unroll
        for (int mt = 0; mt < 4; ++mt)
#pragma unroll
            for (int t1 = 0; t1 < 2; ++t1) {
                uint4 u = w2p[((l * 8 + h * 4 + mt) * 4 + kh * 2 + t1) * 64 + lane];
                a2[mt][t1] = __builtin_bit_cast(v8s, u);
            }
    }
    // bias fragments (prepped layout): 2 + 4 vector loads
    float4 kb1v[2], kb2v[4];
    {
        const float4* p1 = (const float4*)(kb1f + ((size_t)(l * 4 + w) * 64 + lane) * 8);
        kb1v[0] = p1[0];
        kb1v[1] = p1[1];
        const float4* p2 = (const float4*)(kb2f + ((size_t)(l * 4 + w) * 64 + lane) * 16);
#pragma unroll
        for (int mt = 0; mt < 4; ++mt) kb2v[mt] = p2[mt];
    }

    // stage dists into B-frag order: float4 gather + b128 LDS writes (no bank conflicts)
    {
        const float* dg = dists + (size_t)bid * (NPART * NBASIS);
        for (int jt = w; jt < 5; jt += 4) {
            const float* dj = dg + (jt * 16 + c) * 32 + q * 8;
            float4 v0 = *(const float4*)dj;
            float4 v1 = *(const float4*)(dj + 4);
            uint4 pk;
            pk.x = pk2(v0.x, v0.y);
            pk.y = pk2(v0.z, v0.w);
            pk.z = pk2(v1.x, v1.y);
            pk.w = pk2(v1.z, v1.w);
            *(uint4*)(s_dists + (jt * 64 + lane) * 8) = pk;
        }
    }
    __syncthreads();

    // GEMM1-T: 10 MFMA, fast ssp, write X1 B-frags
#pragma unroll
    for (int jt = 0; jt < 5; ++jt) {
        v8s bd = *(const v8s*)(s_dists + (jt * 64 + lane) * 8);
#pragma unroll
        for (int t1 = 0; t1 < 2; ++t1) {
            v4f d = {kb1v[t1].x, kb1v[t1].y, kb1v[t1].z, kb1v[t1].w};
            d = __builtin_amdgcn_mfma_f32_16x16x32_bf16(a1[t1], bd, d, 0, 0, 0);
            uint2 o;
            o.x = pk2(sspf(d[0]), sspf(d[1]));
            o.y = pk2(sspf(d[2]), sspf(d[3]));
            int qB = 2 * t1 + (q >> 1);
            *(uint2*)(s_X1 + ((jt * 4 + w) * 64 + qB * 16 + c) * 8 + (q & 1) * 4) = o;
        }
    }
    __syncthreads();

    // GEMM2-T: 40 MFMA over (4 mt', 5 jt, 2 ks)
    v4f acc[4][5];
#pragma unroll
    for (int mt = 0; mt < 4; ++mt)
#pragma unroll
        for (int jt = 0; jt < 5; ++jt)
            acc[mt][jt] = (v4f){kb2v[mt].x, kb2v[mt].y, kb2v[mt].z, kb2v[mt].w};

#pragma unroll
    for (int jt = 0; jt < 5; ++jt) {
        v8s bx0 = *(const v8s*)(s_X1 + ((jt * 4 + kh * 2) * 64 + lane) * 8);
        v8s bx1 = *(const v8s*)(s_X1 + ((jt * 4 + kh * 2 + 1) * 64 + lane) * 8);
#pragma unroll
        for (int mt = 0; mt < 4; ++mt) {
            acc[mt][jt] = __builtin_amdgcn_mfma_f32_16x16x32_bf16(a2[mt][0], bx0, acc[mt][jt], 0, 0, 0);
            acc[mt][jt] = __builtin_amdgcn_mfma_f32_16x16x32_bf16(a2[mt][1], bx1, acc[mt][jt], 0, 0, 0);
        }
    }

    // multiply by zs (bf16, straight from L2) and reduce over j
    float red[4][4];
#pragma unroll
    for (int mt = 0; mt < 4; ++mt)
#pragma unroll
        for (int r = 0; r < 4; ++r) red[mt][r] = 0.0f;

    const unsigned short* zb = zsbf + (size_t)b * (NPART * KD);
#pragma unroll
    for (int jt = 0; jt < 5; ++jt) {
        const int j = jt * 16 + c;
        const bool msk = (j == i);
#pragma unroll
        for (int mt = 0; mt < 4; ++mt) {
            ushort4 zv = *(const ushort4*)(zb + j * 128 + (h * 4 + mt) * 16 + q * 4);
            if (msk) { zv.x = 0; zv.y = 0; zv.z = 0; zv.w = 0; }
            red[mt][0] += acc[mt][jt][0] * bf2f(zv.x);
            red[mt][1] += acc[mt][jt][1] * bf2f(zv.y);
            red[mt][2] += acc[mt][jt][2] * bf2f(zv.z);
            red[mt][3] += acc[mt][jt][3] * bf2f(zv.w);
        }
    }

    // distributed butterfly: 16 values -> 1 per lane (lane c gets value v=c)
    float vals[16];
#pragma unroll
    for (int m = 0; m < 4; ++m)
#pragma unroll
        for (int r = 0; r < 4; ++r) vals[m * 4 + r] = red[m][r];
#pragma unroll
    for (int B = 0; B < 4; ++B) {
        const int off = 1 << B;
        const bool up = (c >> B) & 1;
#pragma unroll
        for (int k2 = 0; k2 < (8 >> B); ++k2) {
            float aa = vals[2 * k2], bb = vals[2 * k2 + 1];
            float mine = up ? bb : aa;
            float other = up ? aa : bb;
            vals[k2] = mine + __shfl_xor(other, off, 64);
        }
    }
    s_red[w * 64 + ((c >> 2) * 16 + q * 4 + (c & 3))] = vals[0];
    __syncthreads();

    if (t < 128) {
        int hh = t >> 6, kk = t & 63;
        aggbf[(size_t)bid * 128 + t] = f2bf(s_red[hh * 128 + kk] + s_red[hh * 128 + 64 + kk]);
    }
}

extern "C" void kernel_launch(void* const* d_in, const int* in_sizes, int n_in,
                              void* d_out, int out_size, void* d_ws, size_t ws_size,
                              hipStream_t stream) {
    const float* dists = (const float*)d_in[0];
    const float* emb_e = (const float*)d_in[1];
    const float* emb_n = (const float*)d_in[2];
    const float* kW1   = (const float*)d_in[3];
    const float* kb1   = (const float*)d_in[4];
    const float* kW2   = (const float*)d_in[5];
    const float* kb2   = (const float*)d_in[6];
    const float* eiW   = (const float*)d_in[7];
    const float* eoW1  = (const float*)d_in[8];
    const float* eob1  = (const float*)d_in[9];
    const float* eoW2  = (const float*)d_in[10];
    const float* eob2  = (const float*)d_in[11];

    float* xs = (float*)d_out;                                  // (256,64,128) f32
    unsigned short* zsbf  = (unsigned short*)d_ws;              // (256,80,128) bf16
    unsigned short* aggbf = zsbf + NBS * NPART * KD;            // (256,64,128) bf16
    unsigned short* hbf   = aggbf + NBS * NELEC * KD;           // (256,64,128) bf16
    unsigned short* xs_bf = hbf + NBS * NELEC * KD;             // (256,64,128) bf16
    unsigned short* kW1Tf = xs_bf + NBS * NELEC * KD;           // 3*4096
    unsigned short* kW2Tf = kW1Tf + 3 * 4096;                   // 3*16384
    unsigned short* Wf    = kW2Tf + 3 * 16384;                  // 9*16384
    float* kb1f = (float*)(Wf + 9 * 16384);                     // 6144 f32
    float* kb2f = kb1f + 3 * 4 * 64 * 8;                        // 12288 f32

    k_init_xs<<<(NBS * NELEC * DD) / 256, 256, 0, stream>>>(emb_e, xs, xs_bf);
    k_prep<<<3, 256, 0, stream>>>(kW1, kW2, kW1Tf, kW2Tf);
    k_prep_w<<<9, 256, 0, stream>>>(eiW, eoW1, eoW2, Wf);
    k_prep_misc<<<1, 256, 0, stream>>>(kb1, kb2, kb1f, kb2f);
    k_nuc<<<(NBS * 16 * KD) / 256, 256, 0, stream>>>(emb_n, zsbf);

    for (int l = 0; l < 3; ++l) {
        // zs[:, :64] (bf16) = xs_bf @ eiW[l]
        k_gemm<0><<<NBS * 2, 256, 0, stream>>>(
            xs_bf, Wf + (size_t)(0 * 3 + l) * 16384, nullptr, zsbf, nullptr, NPART * KD);

        k_cfconv_mfma<<<NBS * NELEC, 256, 0, stream>>>(
            dists, kb1f, kb2f, zsbf, kW1Tf, kW2Tf, aggbf, l);

        // h (bf16) = ssp(agg @ eoW1 + eob1)
        k_gemm<1><<<NBS * 2, 256, 0, stream>>>(
            aggbf, Wf + (size_t)(1 * 3 + l) * 16384, eob1 + l * DD, hbf, nullptr, NELEC * KD);

        // xs += h @ eoW2 + eob2   (f32 master + bf16 mirror)
        k_gemm<2><<<NBS * 2, 256, 0, stream>>>(
            hbf, Wf + (size_t)(2 * 3 + l) * 16384, eob2 + l * DD, xs_bf, xs, NELEC * KD);
    }
}

// Round 4
// 679.350 us; speedup vs baseline: 8.8484x; 1.6479x over previous
//
#include <hip/hip_runtime.h>

#define NBS    256
#define NELEC  64
#define NPART  80
#define NBASIS 32
#define KD     128
#define DD     128
#define IB     8     // i's per cfconv block

typedef short v8s __attribute__((ext_vector_type(8)));
typedef float v4f __attribute__((ext_vector_type(4)));

// fast shifted softplus: log(1+e^x) - ln2 via HW exp2/log2 (inputs bounded, |x| << 88)
__device__ __forceinline__ float sspf(float x) {
    float t = __expf(x);
    return __logf(1.0f + t) - 0.69314718055994530942f;
}

__device__ __forceinline__ float bf2f(unsigned short u) {
    unsigned int x = ((unsigned int)u) << 16;
    return __builtin_bit_cast(float, x);
}
__device__ __forceinline__ unsigned short f2bf(float f) {
    unsigned int x = __builtin_bit_cast(unsigned int, f);
    x += 0x7fffu + ((x >> 16) & 1u);
    return (unsigned short)(x >> 16);
}
__device__ __forceinline__ unsigned int pk2(float lo, float hi) {
    return (unsigned int)f2bf(lo) | ((unsigned int)f2bf(hi) << 16);
}

// xs[b,i,:] = embedding_elec[i,:] (f32 master + bf16 mirror)
__global__ __launch_bounds__(256) void k_init_xs(const float* __restrict__ emb,
                                                 float* __restrict__ xs,
                                                 unsigned short* __restrict__ xs_bf) {
    int idx = blockIdx.x * 256 + threadIdx.x;
    float v = emb[idx & (NELEC * DD - 1)];
    xs[idx] = v;
    xs_bf[idx] = f2bf(v);
}

// zsbf nuc rows: zsbf[b, 64+j, k] = bf16(nuc[j,k])
__global__ __launch_bounds__(256) void k_nuc(const float* __restrict__ nuc,
                                             unsigned short* __restrict__ zsbf) {
    int idx = blockIdx.x * 256 + threadIdx.x;           // < 256*16*128
    int b = idx >> 11;
    int rem = idx & 2047;
    zsbf[(size_t)b * (NPART * KD) + NELEC * KD + rem] = f2bf(nuc[rem]);
}

// Pre-swizzle kW1/kW2 (per layer) into MFMA A-operand fragment order, bf16.
// A-frag: lane holds A[m = lane&15][k = (lane>>4)*8 + jj], jj=0..7.
// kW2Tf layout: [l][mt'(8)][ks(4)][lane(64)][jj(8)]  (A'[kcol][kf] = kW2[kf][kcol])
// kW1Tf layout: [l][kct(8)][lane(64)][jj(8)]         (A'[kcol][f]  = kW1[f][kcol])
__global__ __launch_bounds__(256) void k_prep(const float* __restrict__ kW1g,
                                              const float* __restrict__ kW2g,
                                              unsigned short* __restrict__ kW1Tf,
                                              unsigned short* __restrict__ kW2Tf) {
    const int l = blockIdx.x;
    const int t = threadIdx.x;
    for (int e = 0; e < 64; ++e) {
        int o = e * 256 + t;                       // < 16384
        int mt = o >> 11, ks = (o >> 9) & 3, lane = (o >> 3) & 63, jj = o & 7;
        int q = lane >> 4, cc = lane & 15;
        int kf = ks * 32 + q * 8 + jj;
        int kcol = mt * 16 + cc;
        kW2Tf[(size_t)l * 16384 + o] = f2bf(kW2g[(size_t)l * 16384 + kf * 128 + kcol]);
    }
    for (int e = 0; e < 16; ++e) {
        int o = e * 256 + t;                       // < 4096
        int kct = o >> 9, lane = (o >> 3) & 63, jj = o & 7;
        int q = lane >> 4, cc = lane & 15;
        int f = q * 8 + jj;
        int kcol = kct * 16 + cc;
        kW1Tf[(size_t)l * 4096 + o] = f2bf(kW1g[(size_t)l * 4096 + f * 128 + kcol]);
    }
}

// B-operand fragment swizzle for the small gemms' weights (9 matrices 128x128).
// Wf[bi][mt(8)][ks(4)][lane(64)][jj(8)] = W[ks*32+q*8+jj][mt*16+c]
__global__ __launch_bounds__(256) void k_prep_w(const float* __restrict__ eiW,
                                                const float* __restrict__ eoW1,
                                                const float* __restrict__ eoW2,
                                                unsigned short* __restrict__ Wf) {
    const int bi = blockIdx.x;          // 0..8 : which*3 + l
    const int which = bi / 3, l = bi % 3;
    const float* src = (which == 0 ? eiW : which == 1 ? eoW1 : eoW2) + (size_t)l * 16384;
    unsigned short* dst = Wf + (size_t)bi * 16384;
    const int t = threadIdx.x;
    for (int e = 0; e < 64; ++e) {
        int o = e * 256 + t;
        int mt = o >> 11, ks = (o >> 9) & 3, lane = (o >> 3) & 63, jj = o & 7;
        int q = lane >> 4, cc = lane & 15;
        dst[o] = f2bf(src[(ks * 32 + q * 8 + jj) * 128 + mt * 16 + cc]);
    }
}

// bias fragments for cfconv (no k-split now): both kb1f and kb2f are
// [l][w(4)][lane(64)][e(8)]: e = mt*4+r -> kb[l*128 + (2*w+mt)*16 + q*4 + r]
__global__ __launch_bounds__(256) void k_prep_misc(const float* __restrict__ kb1,
                                                   const float* __restrict__ kb2,
                                                   float* __restrict__ kb1f,
                                                   float* __restrict__ kb2f) {
    const int t = threadIdx.x;
    for (int o = t; o < 3 * 4 * 64 * 8; o += 256) {
        int l = o >> 11, rem = o & 2047;
        int w = rem >> 9, lane = (rem >> 3) & 63, e = o & 7;
        int mt = e >> 2, r = e & 3, q = lane >> 4;
        int kcol = (2 * w + mt) * 16 + q * 4 + r;
        kb1f[o] = kb1[l * 128 + kcol];
        kb2f[o] = kb2[l * 128 + kcol];
    }
}

// MFMA small gemm: C(64x128) = X(64x128,bf16) @ W(frag bf16)  [+bias][+ssp]
// MODE 0: zs; MODE 1: h (bias+ssp); MODE 2: xs += C (f32 master + bf16 mirror)
template <int MODE>
__global__ __launch_bounds__(256) void k_gemm(
    const unsigned short* __restrict__ Xbf,
    const unsigned short* __restrict__ Wf,
    const float* __restrict__ bias,
    unsigned short* __restrict__ Obf,
    float* __restrict__ Of,
    int ostride) {
    const int blk = blockIdx.x;
    const int b = blk >> 1, kh2 = blk & 1;
    const int t = threadIdx.x, lane = t & 63, w = t >> 6;
    const int q = lane >> 4, c = lane & 15;

    const unsigned short* xb = Xbf + (size_t)b * (NELEC * KD);
    v8s A[4];
#pragma unroll
    for (int ks = 0; ks < 4; ++ks)
        A[ks] = *(const v8s*)(xb + (w * 16 + c) * 128 + ks * 32 + q * 8);

#pragma unroll
    for (int kt = 0; kt < 4; ++kt) {
        const int n0 = kh2 * 64 + kt * 16;
        float bv = (MODE >= 1) ? bias[n0 + c] : 0.0f;
        v4f acc = {bv, bv, bv, bv};
#pragma unroll
        for (int ks = 0; ks < 4; ++ks) {
            v8s B = *(const v8s*)(Wf + (((size_t)(kh2 * 4 + kt) * 4 + ks) * 64 + lane) * 8);
            acc = __builtin_amdgcn_mfma_f32_16x16x32_bf16(A[ks], B, acc, 0, 0, 0);
        }
#pragma unroll
        for (int r = 0; r < 4; ++r) {
            float v = acc[r];
            if (MODE == 1) v = sspf(v);
            int row = w * 16 + q * 4 + r, col = n0 + c;
            if (MODE == 2) {
                size_t o = (size_t)b * (NELEC * KD) + row * 128 + col;
                float nv = Of[o] + v;
                Of[o] = nv;
                Obf[o] = f2bf(nv);
            } else {
                Obf[(size_t)b * ostride + row * 128 + col] = f2bf(v);
            }
        }
    }
}

// One block per (b, group of IB i's). Transposed MFMA formulation, no k-split:
// wave w owns kcols [w*32, w*32+32) (tiles 2w, 2w+1) with the FULL K sum.
//   GEMM1-T: X1T[kcol][j] = ssp( sum_f kW1T[kcol][f]*dists[j][f] + kb1[kcol] )
//   GEMM2-T: WsT[kcol][j] = sum_kf kW2T[kcol][kf]*X1T[kf][j] + kb2[kcol]
//   agg[kcol] = sum_j WsT[kcol][j]*zs[b][j][kcol]  (j==i masked via acc zeroing)
// zs, weights, biases are loaded ONCE per block and reused across IB i's.
__global__ __launch_bounds__(256, 2) void k_cfconv_mfma(
    const float* __restrict__ dists,
    const float* __restrict__ kb1f, const float* __restrict__ kb2f,
    const unsigned short* __restrict__ zsbf,
    const unsigned short* __restrict__ kW1Tf,
    const unsigned short* __restrict__ kW2Tf,
    unsigned short* __restrict__ aggbf, int l) {
    __shared__ __align__(16) unsigned short s_dists[2560];   // [jt(5)][lane(64)][jj(8)]
    __shared__ __align__(16) unsigned short s_X1[10240];     // [jt(5)][ks(4)][lane(64)][jj(8)]

    const int blk = blockIdx.x;
    const int b = blk >> 3;          // 64/IB = 8 groups
    const int ig = blk & 7;
    const int t = threadIdx.x;
    const int lane = t & 63;
    const int w = t >> 6;
    const int q = lane >> 4;
    const int c = lane & 15;

    // --- per-block prelude: weights, biases, zs (amortized over IB i's) ---
    v8s a1[2], a2[2][4];
    {
        const uint4* w1p = (const uint4*)kW1Tf;
        const uint4* w2p = (const uint4*)kW2Tf;
#pragma unroll
        for (int t1 = 0; t1 < 2; ++t1) {
            uint4 u = w1p[(l * 8 + 2 * w + t1) * 64 + lane];
            a1[t1] = __builtin_bit_cast(v8s, u);
        }
#pragma unroll
        for (int mt = 0; mt < 2; ++mt)
#pragma unroll
            for (int ks = 0; ks < 4; ++ks) {
                uint4 u = w2p[((l * 8 + 2 * w + mt) * 4 + ks) * 64 + lane];
                a2[mt][ks] = __builtin_bit_cast(v8s, u);
            }
    }
    float4 kb1v[2], kb2v[2];
    {
        const float4* p1 = (const float4*)(kb1f + ((size_t)(l * 4 + w) * 64 + lane) * 8);
        kb1v[0] = p1[0];
        kb1v[1] = p1[1];
        const float4* p2 = (const float4*)(kb2f + ((size_t)(l * 4 + w) * 64 + lane) * 8);
        kb2v[0] = p2[0];
        kb2v[1] = p2[1];
    }
    // zs values exactly at this lane's reduce positions: row j=jt*16+c, col w*32+mt*16+q*4+r
    float zf[2][5][4];
    {
        const unsigned short* zb = zsbf + (size_t)b * (NPART * KD) + w * 32 + q * 4;
#pragma unroll
        for (int mt = 0; mt < 2; ++mt)
#pragma unroll
            for (int jt = 0; jt < 5; ++jt) {
                ushort4 zv = *(const ushort4*)(zb + (jt * 16 + c) * 128 + mt * 16);
                zf[mt][jt][0] = bf2f(zv.x);
                zf[mt][jt][1] = bf2f(zv.y);
                zf[mt][jt][2] = bf2f(zv.z);
                zf[mt][jt][3] = bf2f(zv.w);
            }
    }

    const float* dbase = dists + ((size_t)b * NELEC + ig * IB) * (NPART * NBASIS);

#pragma unroll 1
    for (int ii = 0; ii < IB; ++ii) {
        const int i = ig * IB + ii;

        // stage dists(b,i) into B-frag order: float4 gather + b128 LDS writes
        {
            const float* dg = dbase + (size_t)ii * (NPART * NBASIS);
            for (int jt = w; jt < 5; jt += 4) {
                const float* dj = dg + (jt * 16 + c) * 32 + q * 8;
                float4 v0 = *(const float4*)dj;
                float4 v1 = *(const float4*)(dj + 4);
                uint4 pk;
                pk.x = pk2(v0.x, v0.y);
                pk.y = pk2(v0.z, v0.w);
                pk.z = pk2(v1.x, v1.y);
                pk.w = pk2(v1.z, v1.w);
                *(uint4*)(s_dists + (jt * 64 + lane) * 8) = pk;
            }
        }
        __syncthreads();

        // GEMM1-T: 10 MFMA, ssp, write X1 B-frags (b64, exact frag order)
#pragma unroll
        for (int jt = 0; jt < 5; ++jt) {
            v8s bd = *(const v8s*)(s_dists + (jt * 64 + lane) * 8);
#pragma unroll
            for (int t1 = 0; t1 < 2; ++t1) {
                v4f d = {kb1v[t1].x, kb1v[t1].y, kb1v[t1].z, kb1v[t1].w};
                d = __builtin_amdgcn_mfma_f32_16x16x32_bf16(a1[t1], bd, d, 0, 0, 0);
                uint2 o;
                o.x = pk2(sspf(d[0]), sspf(d[1]));
                o.y = pk2(sspf(d[2]), sspf(d[3]));
                int qB = 2 * t1 + (q >> 1);   // ks slice = w (wave owns kcols w*32..)
                *(uint2*)(s_X1 + ((jt * 4 + w) * 64 + qB * 16 + c) * 8 + (q & 1) * 4) = o;
            }
        }
        __syncthreads();

        // GEMM2-T: 40 MFMA over (2 mt, 5 jt, 4 ks), full K sum per wave
        v4f acc[2][5];
#pragma unroll
        for (int mt = 0; mt < 2; ++mt)
#pragma unroll
            for (int jt = 0; jt < 5; ++jt)
                acc[mt][jt] = (v4f){(&kb2v[mt].x)[0], (&kb2v[mt].x)[1],
                                    (&kb2v[mt].x)[2], (&kb2v[mt].x)[3]};

#pragma unroll
        for (int jt = 0; jt < 5; ++jt) {
#pragma unroll
            for (int ks = 0; ks < 4; ++ks) {
                v8s bx = *(const v8s*)(s_X1 + ((jt * 4 + ks) * 64 + lane) * 8);
                acc[0][jt] = __builtin_amdgcn_mfma_f32_16x16x32_bf16(a2[0][ks], bx, acc[0][jt], 0, 0, 0);
                acc[1][jt] = __builtin_amdgcn_mfma_f32_16x16x32_bf16(a2[1][ks], bx, acc[1][jt], 0, 0, 0);
            }
        }

        // mask j==i (zero this i's acc at jt=i>>4, lane c=i&15), then reduce over j
        float red[8];
#pragma unroll
        for (int v = 0; v < 8; ++v) red[v] = 0.0f;
#pragma unroll
        for (int jt = 0; jt < 5; ++jt) {
            const bool dead = (jt * 16 + c) == i;
#pragma unroll
            for (int mt = 0; mt < 2; ++mt)
#pragma unroll
                for (int r = 0; r < 4; ++r) {
                    float a = dead ? 0.0f : acc[mt][jt][r];
                    red[mt * 4 + r] += a * zf[mt][jt][r];
                }
        }

        // butterfly: 8 vals -> lane c holds value (c&7) summed over its 8-lane half,
        // then xor-8 add completes the 16-lane j sum.
        float vals[8];
#pragma unroll
        for (int v = 0; v < 8; ++v) vals[v] = red[v];
#pragma unroll
        for (int B = 0; B < 3; ++B) {
            const int off = 1 << B;
            const bool up = (c >> B) & 1;
#pragma unroll
            for (int k2 = 0; k2 < (4 >> B); ++k2) {
                float aa = vals[2 * k2], bb = vals[2 * k2 + 1];
                float mine = up ? bb : aa;
                float other = up ? aa : bb;
                vals[k2] = mine + __shfl_xor(other, off, 64);
            }
        }
        float x = vals[0] + __shfl_xor(vals[0], 8, 64);

        // lanes c<8 write this wave's 32 kcols: kcol = w*32 + ((c>>2)&1)*16 + q*4 + (c&3)
        if (c < 8) {
            int kcol = w * 32 + ((c >> 2) & 1) * 16 + q * 4 + (c & 3);
            aggbf[((size_t)b * NELEC + i) * 128 + kcol] = f2bf(x);
        }
    }
}

extern "C" void kernel_launch(void* const* d_in, const int* in_sizes, int n_in,
                              void* d_out, int out_size, void* d_ws, size_t ws_size,
                              hipStream_t stream) {
    const float* dists = (const float*)d_in[0];
    const float* emb_e = (const float*)d_in[1];
    const float* emb_n = (const float*)d_in[2];
    const float* kW1   = (const float*)d_in[3];
    const float* kb1   = (const float*)d_in[4];
    const float* kW2   = (const float*)d_in[5];
    const float* kb2   = (const float*)d_in[6];
    const float* eiW   = (const float*)d_in[7];
    const float* eoW1  = (const float*)d_in[8];
    const float* eob1  = (const float*)d_in[9];
    const float* eoW2  = (const float*)d_in[10];
    const float* eob2  = (const float*)d_in[11];

    float* xs = (float*)d_out;                                  // (256,64,128) f32
    unsigned short* zsbf  = (unsigned short*)d_ws;              // (256,80,128) bf16
    unsigned short* aggbf = zsbf + NBS * NPART * KD;            // (256,64,128) bf16
    unsigned short* hbf   = aggbf + NBS * NELEC * KD;           // (256,64,128) bf16
    unsigned short* xs_bf = hbf + NBS * NELEC * KD;             // (256,64,128) bf16
    unsigned short* kW1Tf = xs_bf + NBS * NELEC * KD;           // 3*4096
    unsigned short* kW2Tf = kW1Tf + 3 * 4096;                   // 3*16384
    unsigned short* Wf    = kW2Tf + 3 * 16384;                  // 9*16384
    float* kb1f = (float*)(Wf + 9 * 16384);                     // 6144 f32
    float* kb2f = kb1f + 3 * 4 * 64 * 8;                        // 6144 f32

    k_init_xs<<<(NBS * NELEC * DD) / 256, 256, 0, stream>>>(emb_e, xs, xs_bf);
    k_prep<<<3, 256, 0, stream>>>(kW1, kW2, kW1Tf, kW2Tf);
    k_prep_w<<<9, 256, 0, stream>>>(eiW, eoW1, eoW2, Wf);
    k_prep_misc<<<1, 256, 0, stream>>>(kb1, kb2, kb1f, kb2f);
    k_nuc<<<(NBS * 16 * KD) / 256, 256, 0, stream>>>(emb_n, zsbf);

    for (int l = 0; l < 3; ++l) {
        // zs[:, :64] (bf16) = xs_bf @ eiW[l]
        k_gemm<0><<<NBS * 2, 256, 0, stream>>>(
            xs_bf, Wf + (size_t)(0 * 3 + l) * 16384, nullptr, zsbf, nullptr, NPART * KD);

        k_cfconv_mfma<<<NBS * (NELEC / IB), 256, 0, stream>>>(
            dists, kb1f, kb2f, zsbf, kW1Tf, kW2Tf, aggbf, l);

        // h (bf16) = ssp(agg @ eoW1 + eob1)
        k_gemm<1><<<NBS * 2, 256, 0, stream>>>(
            aggbf, Wf + (size_t)(1 * 3 + l) * 16384, eob1 + l * DD, hbf, nullptr, NELEC * KD);

        // xs += h @ eoW2 + eob2   (f32 master + bf16 mirror)
        k_gemm<2><<<NBS * 2, 256, 0, stream>>>(
            hbf, Wf + (size_t)(2 * 3 + l) * 16384, eob2 + l * DD, xs_bf, xs, NELEC * KD);
    }
}